// Round 1
// baseline (1105.287 us; speedup 1.0000x reference)
//
#include <hip/hip_runtime.h>
#include <math.h>

#define NSRC 100000
#define NDST 100000
#define NE   1600000
#define IND  128
#define OUTD 64
#define SLOPE 0.01f

// Monotone float -> uint mapping so segment-max can use atomicMax(uint).
// key(f) is strictly increasing in f; key=0 is below every real float's key,
// so memset(0) is the max-identity.
__device__ __forceinline__ unsigned fkey(float f) {
    unsigned b = __float_as_uint(f);
    return (b & 0x80000000u) ? ~b : (b | 0x80000000u);
}
__device__ __forceinline__ float funkey(unsigned k) {
    unsigned b = (k & 0x80000000u) ? (k & 0x7FFFFFFFu) : ~k;
    return __uint_as_float(b);
}

// v_dst[k] = sum_o W_dst[o][k] * a_r[o]   (folds z_dst@a_r into h_dst@v_dst)
__global__ void k_vdst(const float* __restrict__ W_dst,
                       const float* __restrict__ attn_w,
                       float* __restrict__ v_dst) {
    int k = threadIdx.x;  // 128 threads
    float acc = 0.f;
#pragma unroll 8
    for (int o = 0; o < OUTD; ++o)
        acc = fmaf(W_dst[o * IND + k], attn_w[OUTD + o], acc);
    v_dst[k] = acc;
}

// z_src = h_src @ W_src^T (optionally softplus), el = z_src @ a_l
// 4 waves/block, one row per wave, lane o computes output dim o.
// W stored transposed in LDS: Wt[k][o] -> lanes read consecutive o (2-way = free).
__global__ __launch_bounds__(256) void k_zsrc(const float* __restrict__ h_src,
                                              const float* __restrict__ W_src,
                                              const float* __restrict__ attn_w,
                                              const int* __restrict__ item_user,
                                              float* __restrict__ z_src,
                                              float* __restrict__ el) {
    __shared__ float Wt[IND * OUTD];   // 32 KB
    __shared__ float hrow[4][IND];
    const int tid = threadIdx.x;
#pragma unroll
    for (int it = 0; it < (IND * OUTD) / 256; ++it) {
        int idx = it * 256 + tid;          // coalesced read of W_src
        int o = idx >> 7, k = idx & 127;
        Wt[k * OUTD + o] = W_src[idx];
    }
    const int wave = tid >> 6, lane = tid & 63;
    const int row = blockIdx.x * 4 + wave;   // grid = 25000 -> exactly 100000 rows
    hrow[wave][lane]      = h_src[row * IND + lane];
    hrow[wave][lane + 64] = h_src[row * IND + lane + 64];
    __syncthreads();

    float acc = 0.f;
#pragma unroll 16
    for (int k = 0; k < IND; ++k)
        acc = fmaf(hrow[wave][k], Wt[k * OUTD + lane], acc);

    if (*item_user) {  // softplus (stable); wave-uniform branch
        acc = (acc > 20.f) ? acc : log1pf(__expf(acc));
    }
    z_src[row * OUTD + lane] = acc;

    float t = acc * attn_w[lane];   // a_l[lane]
#pragma unroll
    for (int off = 32; off; off >>= 1) t += __shfl_down(t, off);
    if (lane == 0) el[row] = t;
}

// er[row] = h_dst[row] . v_dst   (wave per row, float2 loads)
__global__ __launch_bounds__(256) void k_er(const float* __restrict__ h_dst,
                                            const float* __restrict__ v_dst,
                                            float* __restrict__ er) {
    __shared__ float v[IND];
    const int tid = threadIdx.x;
    if (tid < IND) v[tid] = v_dst[tid];
    __syncthreads();
    const int wave = tid >> 6, lane = tid & 63;
    const int row = blockIdx.x * 4 + wave;
    const float2 h2 = *(const float2*)(h_dst + row * IND + lane * 2);
    float t = fmaf(h2.x, v[lane * 2], h2.y * v[lane * 2 + 1]);
#pragma unroll
    for (int off = 32; off; off >>= 1) t += __shfl_down(t, off);
    if (lane == 0) er[row] = t;
}

// Edge pass 1: e = leaky_relu(el[s] + er[d]); segment-max into mkey via atomicMax
__global__ void k_edge_max(const int* __restrict__ src, const int* __restrict__ dst,
                           const float* __restrict__ el, const float* __restrict__ er,
                           float* __restrict__ e_buf, unsigned* __restrict__ mkey) {
    int j = blockIdx.x * 256 + threadIdx.x;
    if (j >= NE) return;
    int s = src[j], d = dst[j];
    float e = el[s] + er[d];
    e = (e > 0.f) ? e : SLOPE * e;
    e_buf[j] = e;
    atomicMax(&mkey[d], fkey(e));
}

// Edge pass 2: wave per edge. ex = exp(e - m[d]); denom[d] += ex (lane 0);
// out[d][lane] += ex * z_src[s][lane]
__global__ __launch_bounds__(256) void k_scatter(const int* __restrict__ src,
                                                 const int* __restrict__ dst,
                                                 const float* __restrict__ e_buf,
                                                 const unsigned* __restrict__ mkey,
                                                 const float* __restrict__ z_src,
                                                 float* __restrict__ denom,
                                                 float* __restrict__ out) {
    const int wave = threadIdx.x >> 6, lane = threadIdx.x & 63;
    const int j = blockIdx.x * 4 + wave;   // grid = 400000 -> exactly NE edges
    const int s = src[j], d = dst[j];
    const float ex = __expf(e_buf[j] - funkey(mkey[d]));
    if (lane == 0) atomicAdd(&denom[d], ex);
    atomicAdd(&out[d * OUTD + lane], ex * z_src[s * OUTD + lane]);
}

// Final: out[row][o] /= denom[row]  (empty segments stay 0)
__global__ void k_norm(float* __restrict__ out, const float* __restrict__ denom) {
    int i = blockIdx.x * 256 + threadIdx.x;   // 6.4M elements
    float dn = denom[i >> 6];
    if (dn > 0.f) out[i] /= dn;
}

extern "C" void kernel_launch(void* const* d_in, const int* in_sizes, int n_in,
                              void* d_out, int out_size, void* d_ws, size_t ws_size,
                              hipStream_t stream) {
    const float* h_src   = (const float*)d_in[0];
    const float* h_dst   = (const float*)d_in[1];
    const int*   src_idx = (const int*)d_in[2];
    const int*   dst_idx = (const int*)d_in[3];
    const float* W_src   = (const float*)d_in[4];
    const float* W_dst   = (const float*)d_in[5];
    const float* attn_w  = (const float*)d_in[6];
    const int*   item_u  = (const int*)d_in[7];
    float* out = (float*)d_out;

    // workspace layout (bytes):
    char* ws = (char*)d_ws;
    float*    z_src = (float*)(ws);                  // 25,600,000
    float*    el    = (float*)(ws + 25600000);       //    400,000
    float*    er    = (float*)(ws + 26000000);       //    400,000
    float*    e_buf = (float*)(ws + 26400000);       //  6,400,000
    unsigned* mkey  = (unsigned*)(ws + 32800000);    //    400,000
    float*    denom = (float*)(ws + 33200000);       //    400,000
    float*    v_dst = (float*)(ws + 33600000);       //        512
    // total ~33.6 MB

    hipMemsetAsync(mkey, 0, 800000, stream);     // mkey (max identity) + denom (0)
    hipMemsetAsync(out, 0, (size_t)out_size * sizeof(float), stream);

    k_vdst    <<<1,      128, 0, stream>>>(W_dst, attn_w, v_dst);
    k_zsrc    <<<25000,  256, 0, stream>>>(h_src, W_src, attn_w, item_u, z_src, el);
    k_er      <<<25000,  256, 0, stream>>>(h_dst, v_dst, er);
    k_edge_max<<<6250,   256, 0, stream>>>(src_idx, dst_idx, el, er, e_buf, mkey);
    k_scatter <<<400000, 256, 0, stream>>>(src_idx, dst_idx, e_buf, mkey, z_src, denom, out);
    k_norm    <<<25000,  256, 0, stream>>>(out, denom);
}

// Round 3
// 981.544 us; speedup vs baseline: 1.1261x; 1.1261x over previous
//
#include <hip/hip_runtime.h>
#include <math.h>

#define NSRC 100000
#define NDST 100000
#define NE   1600000
#define IND  128
#define OUTD 64
#define SLOPE 0.01f
#define NTILE 98   // ceil(NDST / 1024)

// ---------------------------------------------------------------------------
// v_dst[k] = sum_o W_dst[o][k] * a_r[o]   (folds z_dst@a_r into h_dst@v_dst)
__global__ void k_vdst(const float* __restrict__ W_dst,
                       const float* __restrict__ attn_w,
                       float* __restrict__ v_dst) {
    int k = threadIdx.x;  // 128 threads
    float acc = 0.f;
#pragma unroll 8
    for (int o = 0; o < OUTD; ++o)
        acc = fmaf(W_dst[o * IND + k], attn_w[OUTD + o], acc);
    v_dst[k] = acc;
}

// ---------------------------------------------------------------------------
// z_src = h_src @ W_src^T (optionally softplus), el = z_src @ a_l
__global__ __launch_bounds__(256) void k_zsrc(const float* __restrict__ h_src,
                                              const float* __restrict__ W_src,
                                              const float* __restrict__ attn_w,
                                              const int* __restrict__ item_user,
                                              float* __restrict__ z_src,
                                              float* __restrict__ el) {
    __shared__ float Wt[IND * OUTD];   // 32 KB, transposed: Wt[k][o]
    __shared__ float hrow[4][IND];
    const int tid = threadIdx.x;
#pragma unroll
    for (int it = 0; it < (IND * OUTD) / 256; ++it) {
        int idx = it * 256 + tid;
        int o = idx >> 7, k = idx & 127;
        Wt[k * OUTD + o] = W_src[idx];
    }
    const int wave = tid >> 6, lane = tid & 63;
    const int row = blockIdx.x * 4 + wave;   // grid 25000 -> exactly NSRC rows
    hrow[wave][lane]      = h_src[row * IND + lane];
    hrow[wave][lane + 64] = h_src[row * IND + lane + 64];
    __syncthreads();

    float acc = 0.f;
#pragma unroll 16
    for (int k = 0; k < IND; ++k)
        acc = fmaf(hrow[wave][k], Wt[k * OUTD + lane], acc);

    if (*item_user) {  // softplus (stable); uniform branch
        acc = (acc > 20.f) ? acc : log1pf(__expf(acc));
    }
    z_src[row * OUTD + lane] = acc;

    float t = acc * attn_w[lane];   // a_l[lane]
#pragma unroll
    for (int off = 32; off; off >>= 1) t += __shfl_down(t, off);
    if (lane == 0) el[row] = t;
}

// ---------------------------------------------------------------------------
// er[row] = h_dst[row] . v_dst
__global__ __launch_bounds__(256) void k_er(const float* __restrict__ h_dst,
                                            const float* __restrict__ v_dst,
                                            float* __restrict__ er) {
    __shared__ float v[IND];
    const int tid = threadIdx.x;
    if (tid < IND) v[tid] = v_dst[tid];
    __syncthreads();
    const int wave = tid >> 6, lane = tid & 63;
    const int row = blockIdx.x * 4 + wave;
    const float2 h2 = *(const float2*)(h_dst + row * IND + lane * 2);
    float t = fmaf(h2.x, v[lane * 2], h2.y * v[lane * 2 + 1]);
#pragma unroll
    for (int off = 32; off; off >>= 1) t += __shfl_down(t, off);
    if (lane == 0) er[row] = t;
}

// ---------------------------------------------------------------------------
__global__ void k_hist(const int* __restrict__ dst, int* __restrict__ cnt) {
    int j = blockIdx.x * 256 + threadIdx.x;
    if (j < NE) atomicAdd(&cnt[dst[j]], 1);
}

__device__ __forceinline__ int wave_incl_scan(int v, int lane) {
#pragma unroll
    for (int off = 1; off < 64; off <<= 1) {
        int u = __shfl_up(v, off);
        if (lane >= off) v += u;
    }
    return v;
}

// Single-block exclusive scan of cnt[0..NDST) -> starts & cursor; starts[NDST]=NE.
// One block, 256 threads, 98 coalesced tiles of 1024 with an LDS carry.
__global__ __launch_bounds__(256) void k_scan(const int* __restrict__ cnt,
                                              int* __restrict__ starts,
                                              int* __restrict__ cursor) {
    __shared__ int wsum[4];
    __shared__ int carry_s;
    const int t = threadIdx.x, wave = t >> 6, lane = t & 63;
    if (t == 0) carry_s = 0;
    __syncthreads();
    for (int tile = 0; tile < NTILE; ++tile) {
        const int base = tile * 1024 + t * 4;
        int v[4];
#pragma unroll
        for (int q = 0; q < 4; ++q) v[q] = (base + q < NDST) ? cnt[base + q] : 0;
        int tsum = v[0] + v[1] + v[2] + v[3];
        int incl = wave_incl_scan(tsum, lane);
        if (lane == 63) wsum[wave] = incl;
        __syncthreads();                       // publish wsum; carry_s stable
        const int carry = carry_s;
        int wbase = 0;
        for (int w = 0; w < wave; ++w) wbase += wsum[w];
        int run = carry + wbase + incl - tsum; // exclusive prefix of this chunk
#pragma unroll
        for (int q = 0; q < 4; ++q) {
            if (base + q < NDST) { starts[base + q] = run; cursor[base + q] = run; }
            run += v[q];
        }
        __syncthreads();                       // all readers of carry_s done
        if (t == 255) carry_s = carry + wbase + incl;
        __syncthreads();                       // publish new carry
    }
    if (t == 0) starts[NDST] = carry_s;        // == NE
}

// ---------------------------------------------------------------------------
__global__ void k_fill(const int* __restrict__ src, const int* __restrict__ dst,
                       int* __restrict__ cursor, int* __restrict__ csr_src) {
    int j = blockIdx.x * 256 + threadIdx.x;
    if (j < NE) {
        int p = atomicAdd(&cursor[dst[j]], 1);
        if ((unsigned)p < (unsigned)NE) csr_src[p] = src[j];
    }
}

// ---------------------------------------------------------------------------
// One wave per dst: max -> exp/denom -> weighted gather-sum, no atomics.
__global__ __launch_bounds__(256) void k_aggregate(const int* __restrict__ starts,
                                                   const int* __restrict__ csr_src,
                                                   const float* __restrict__ el,
                                                   const float* __restrict__ er,
                                                   const float* __restrict__ z_src,
                                                   float* __restrict__ out) {
    const int wave = threadIdx.x >> 6, lane = threadIdx.x & 63;
    const int d = blockIdx.x * 4 + wave;   // grid 25000 -> exactly NDST
    int s0 = starts[d], s1 = starts[d + 1];
    s0 = max(0, min(s0, NE));
    s1 = max(s0, min(s1, NE));
    const int deg = s1 - s0;
    const float er_d = er[d];

    // phase 1: segment max of leaky_relu(el[s] + er[d])
    float m = -INFINITY;
    for (int base = 0; base < deg; base += 64) {
        int i = base + lane;
        float e = -INFINITY;
        if (i < deg) {
            int s = csr_src[s0 + i];
            s = ((unsigned)s < (unsigned)NSRC) ? s : 0;
            e = el[s] + er_d;
            e = (e > 0.f) ? e : SLOPE * e;
        }
#pragma unroll
        for (int off = 32; off; off >>= 1) e = fmaxf(e, __shfl_xor(e, off));
        m = fmaxf(m, e);
    }

    // phase 2: ex, denom, weighted sum of z_src rows
    float acc = 0.f, dsum = 0.f;
    for (int base = 0; base < deg; base += 64) {
        int n = min(64, deg - base);
        int i = base + lane;
        int s = 0;
        float ex = 0.f;
        if (i < deg) {
            s = csr_src[s0 + i];
            s = ((unsigned)s < (unsigned)NSRC) ? s : 0;
            float e = el[s] + er_d;
            e = (e > 0.f) ? e : SLOPE * e;
            ex = __expf(e - m);
        }
        dsum += ex;
        for (int j = 0; j < n; ++j) {
            int sj = __shfl(s, j);
            float exj = __shfl(ex, j);
            acc = fmaf(exj, z_src[sj * OUTD + lane], acc);
        }
    }
#pragma unroll
    for (int off = 32; off; off >>= 1) dsum += __shfl_xor(dsum, off);

    out[d * OUTD + lane] = (deg > 0 && dsum > 0.f) ? acc / dsum : 0.f;
}

// ---------------------------------------------------------------------------
extern "C" void kernel_launch(void* const* d_in, const int* in_sizes, int n_in,
                              void* d_out, int out_size, void* d_ws, size_t ws_size,
                              hipStream_t stream) {
    const float* h_src   = (const float*)d_in[0];
    const float* h_dst   = (const float*)d_in[1];
    const int*   src_idx = (const int*)d_in[2];
    const int*   dst_idx = (const int*)d_in[3];
    const float* W_src   = (const float*)d_in[4];
    const float* W_dst   = (const float*)d_in[5];
    const float* attn_w  = (const float*)d_in[6];
    const int*   item_u  = (const int*)d_in[7];
    float* out = (float*)d_out;

    // workspace layout (bytes), NO aliasing:
    char* ws = (char*)d_ws;
    float* z_src   = (float*)(ws);                 // 25,600,000
    float* el      = (float*)(ws + 25600000);      //    400,000
    float* er      = (float*)(ws + 26000000);      //    400,000
    int*   cnt     = (int*)  (ws + 26400000);      //    400,000
    int*   starts  = (int*)  (ws + 26800000);      //    400,016 (NDST+1, pad)
    int*   cursor  = (int*)  (ws + 27200016);      //    400,000
    int*   csr_src = (int*)  (ws + 27600016);      //  6,400,000
    float* v_dst   = (float*)(ws + 34000016);      //        512
    const size_t WS_USED = 34000528;

    // Start every call from a known-zero workspace & output (the harness
    // poisons d_ws/d_out to 0xAA before timed calls; call-1 state must not
    // be special).
    hipMemsetAsync(ws, 0, WS_USED, stream);
    hipMemsetAsync(out, 0, (size_t)out_size * sizeof(float), stream);

    k_vdst     <<<1,     128, 0, stream>>>(W_dst, attn_w, v_dst);
    k_zsrc     <<<25000, 256, 0, stream>>>(h_src, W_src, attn_w, item_u, z_src, el);
    k_er       <<<25000, 256, 0, stream>>>(h_dst, v_dst, er);
    k_hist     <<<6250,  256, 0, stream>>>(dst_idx, cnt);
    k_scan     <<<1,     256, 0, stream>>>(cnt, starts, cursor);
    k_fill     <<<6250,  256, 0, stream>>>(src_idx, dst_idx, cursor, csr_src);
    k_aggregate<<<25000, 256, 0, stream>>>(starts, csr_src, el, er, z_src, out);
}

// Round 4
// 606.638 us; speedup vs baseline: 1.8220x; 1.6180x over previous
//
#include <hip/hip_runtime.h>
#include <math.h>

#define NSRC 100000
#define NDST 100000
#define NE   1600000
#define IND  128
#define OUTD 64
#define SLOPE 0.01f
#define NTILE 98    // ceil(NDST / 1024)
#define ZGRID 1563  // ceil(NSRC / 64)

__device__ __forceinline__ float softplus_f(float x) {
    return (x > 20.f) ? x : log1pf(__expf(x));
}

// ---------------------------------------------------------------------------
// v_dst[k] = sum_o W_dst[o][k] * a_r[o]   (folds z_dst@a_r into h_dst@v_dst)
__global__ void k_vdst(const float* __restrict__ W_dst,
                       const float* __restrict__ attn_w,
                       float* __restrict__ v_dst) {
    int k = threadIdx.x;  // 128 threads
    float acc = 0.f;
#pragma unroll 8
    for (int o = 0; o < OUTD; ++o)
        acc = fmaf(W_dst[o * IND + k], attn_w[OUTD + o], acc);
    v_dst[k] = acc;
}

// ---------------------------------------------------------------------------
// z_src = h_src @ W_src^T (+softplus), el = z_src @ a_l
// Register-tiled: block = 64 rows x 64 cols, K=128 in 2 phases of 64.
// LDS stride 68 floats: 16B-aligned for b128, and 68 % 32 == 4 so tiled reads
// are <=2-way per bank (free). Thread (rg,cg) owns rows 4rg..+3, cols 4cg..+3.
__global__ __launch_bounds__(256) void k_zsrc(const float* __restrict__ h_src,
                                              const float* __restrict__ W_src,
                                              const float* __restrict__ attn_w,
                                              const int* __restrict__ item_user,
                                              float* __restrict__ z_src,
                                              float* __restrict__ el) {
    __shared__ float4 As4[64 * 17];   // A[r][kk], row stride 17 float4 (68 f)
    __shared__ float4 Ws4[64 * 17];   // Wt[kk][c], row stride 17 float4
    float* Ws = (float*)Ws4;

    const int t   = threadIdx.x;
    const int rg  = t >> 4;       // 0..15
    const int cg  = t & 15;       // 0..15
    const int row0 = blockIdx.x * 64;

    float4 acc[4];
#pragma unroll
    for (int i = 0; i < 4; ++i) acc[i] = float4{0.f, 0.f, 0.f, 0.f};

    for (int p = 0; p < 2; ++p) {
        // stage A chunk: As[r][kk] = h_src[row0+r][64p+kk]  (coalesced float4)
#pragma unroll
        for (int i = 0; i < 4; ++i) {
            int f = i * 256 + t;            // 1024 float4s
            int r = f >> 4, kq = f & 15;
            int row = row0 + r;
            int rowc = (row < NSRC) ? row : (NSRC - 1);
            As4[r * 17 + kq] = *(const float4*)(h_src + rowc * IND + p * 64 + kq * 4);
        }
        // stage W chunk transposed: Ws[kk][o] = W_src[o][64p+kk]
        // (scalar stores, ~8-way bank aliasing on 16 instrs -> negligible)
#pragma unroll
        for (int i = 0; i < 4; ++i) {
            int f = i * 256 + t;
            int o = f >> 4, kq = f & 15;
            float4 w = *(const float4*)(W_src + o * IND + p * 64 + kq * 4);
            Ws[(kq * 4 + 0) * 68 + o] = w.x;
            Ws[(kq * 4 + 1) * 68 + o] = w.y;
            Ws[(kq * 4 + 2) * 68 + o] = w.z;
            Ws[(kq * 4 + 3) * 68 + o] = w.w;
        }
        __syncthreads();

#pragma unroll
        for (int kq = 0; kq < 16; ++kq) {
            float4 w0 = Ws4[(kq * 4 + 0) * 17 + cg];
            float4 w1 = Ws4[(kq * 4 + 1) * 17 + cg];
            float4 w2 = Ws4[(kq * 4 + 2) * 17 + cg];
            float4 w3 = Ws4[(kq * 4 + 3) * 17 + cg];
#pragma unroll
            for (int ri = 0; ri < 4; ++ri) {
                float4 a = As4[(rg * 4 + ri) * 17 + kq];
                acc[ri].x = fmaf(a.x, w0.x, fmaf(a.y, w1.x, fmaf(a.z, w2.x, fmaf(a.w, w3.x, acc[ri].x))));
                acc[ri].y = fmaf(a.x, w0.y, fmaf(a.y, w1.y, fmaf(a.z, w2.y, fmaf(a.w, w3.y, acc[ri].y))));
                acc[ri].z = fmaf(a.x, w0.z, fmaf(a.y, w1.z, fmaf(a.z, w2.z, fmaf(a.w, w3.z, acc[ri].z))));
                acc[ri].w = fmaf(a.x, w0.w, fmaf(a.y, w1.w, fmaf(a.z, w2.w, fmaf(a.w, w3.w, acc[ri].w))));
            }
        }
        __syncthreads();   // before restaging next chunk
    }

    const int iu = *item_user;
    const float4 al = *(const float4*)(attn_w + cg * 4);
#pragma unroll
    for (int ri = 0; ri < 4; ++ri) {
        float4 z = acc[ri];
        if (iu) { z.x = softplus_f(z.x); z.y = softplus_f(z.y);
                  z.z = softplus_f(z.z); z.w = softplus_f(z.w); }
        const int row = row0 + rg * 4 + ri;
        float pl = fmaf(z.x, al.x, fmaf(z.y, al.y, fmaf(z.z, al.z, z.w * al.w)));
        // reduce over the 16 col-group lanes (xor 1,2,4,8 stays in-group)
        pl += __shfl_xor(pl, 1);
        pl += __shfl_xor(pl, 2);
        pl += __shfl_xor(pl, 4);
        pl += __shfl_xor(pl, 8);
        if (row < NSRC) {
            *(float4*)(z_src + row * OUTD + cg * 4) = z;
            if (cg == 0) el[row] = pl;
        }
    }
}

// ---------------------------------------------------------------------------
// er[row] = h_dst[row] . v_dst
__global__ __launch_bounds__(256) void k_er(const float* __restrict__ h_dst,
                                            const float* __restrict__ v_dst,
                                            float* __restrict__ er) {
    __shared__ float v[IND];
    const int tid = threadIdx.x;
    if (tid < IND) v[tid] = v_dst[tid];
    __syncthreads();
    const int wave = tid >> 6, lane = tid & 63;
    const int row = blockIdx.x * 4 + wave;
    const float2 h2 = *(const float2*)(h_dst + row * IND + lane * 2);
    float t = fmaf(h2.x, v[lane * 2], h2.y * v[lane * 2 + 1]);
#pragma unroll
    for (int off = 32; off; off >>= 1) t += __shfl_down(t, off);
    if (lane == 0) er[row] = t;
}

// ---------------------------------------------------------------------------
__global__ void k_hist(const int* __restrict__ dst, int* __restrict__ cnt) {
    int j = blockIdx.x * 256 + threadIdx.x;
    if (j < NE) atomicAdd(&cnt[dst[j]], 1);
}

__device__ __forceinline__ int wave_incl_scan(int v, int lane) {
#pragma unroll
    for (int off = 1; off < 64; off <<= 1) {
        int u = __shfl_up(v, off);
        if (lane >= off) v += u;
    }
    return v;
}

// Single-block exclusive scan of cnt[0..NDST) -> starts & cursor; starts[NDST]=NE.
__global__ __launch_bounds__(256) void k_scan(const int* __restrict__ cnt,
                                              int* __restrict__ starts,
                                              int* __restrict__ cursor) {
    __shared__ int wsum[4];
    __shared__ int carry_s;
    const int t = threadIdx.x, wave = t >> 6, lane = t & 63;
    if (t == 0) carry_s = 0;
    __syncthreads();
    for (int tile = 0; tile < NTILE; ++tile) {
        const int base = tile * 1024 + t * 4;
        int v[4];
#pragma unroll
        for (int q = 0; q < 4; ++q) v[q] = (base + q < NDST) ? cnt[base + q] : 0;
        int tsum = v[0] + v[1] + v[2] + v[3];
        int incl = wave_incl_scan(tsum, lane);
        if (lane == 63) wsum[wave] = incl;
        __syncthreads();
        const int carry = carry_s;
        int wbase = 0;
        for (int w = 0; w < wave; ++w) wbase += wsum[w];
        int run = carry + wbase + incl - tsum;
#pragma unroll
        for (int q = 0; q < 4; ++q) {
            if (base + q < NDST) { starts[base + q] = run; cursor[base + q] = run; }
            run += v[q];
        }
        __syncthreads();
        if (t == 255) carry_s = carry + wbase + incl;
        __syncthreads();
    }
    if (t == 0) starts[NDST] = carry_s;
}

// ---------------------------------------------------------------------------
__global__ void k_fill(const int* __restrict__ src, const int* __restrict__ dst,
                       int* __restrict__ cursor, int* __restrict__ csr_src) {
    int j = blockIdx.x * 256 + threadIdx.x;
    if (j < NE) {
        int p = atomicAdd(&cursor[dst[j]], 1);
        if ((unsigned)p < (unsigned)NE) csr_src[p] = src[j];
    }
}

// ---------------------------------------------------------------------------
// One wave per dst: max -> exp/denom -> weighted gather-sum, no atomics.
__global__ __launch_bounds__(256) void k_aggregate(const int* __restrict__ starts,
                                                   const int* __restrict__ csr_src,
                                                   const float* __restrict__ el,
                                                   const float* __restrict__ er,
                                                   const float* __restrict__ z_src,
                                                   float* __restrict__ out) {
    const int wave = threadIdx.x >> 6, lane = threadIdx.x & 63;
    const int d = blockIdx.x * 4 + wave;   // grid 25000 -> exactly NDST
    int s0 = starts[d], s1 = starts[d + 1];
    s0 = max(0, min(s0, NE));
    s1 = max(s0, min(s1, NE));
    const int deg = s1 - s0;
    const float er_d = er[d];

    // phase 1: segment max of leaky_relu(el[s] + er[d])
    float m = -INFINITY;
    for (int base = 0; base < deg; base += 64) {
        int i = base + lane;
        float e = -INFINITY;
        if (i < deg) {
            int s = csr_src[s0 + i];
            s = ((unsigned)s < (unsigned)NSRC) ? s : 0;
            e = el[s] + er_d;
            e = (e > 0.f) ? e : SLOPE * e;
        }
#pragma unroll
        for (int off = 32; off; off >>= 1) e = fmaxf(e, __shfl_xor(e, off));
        m = fmaxf(m, e);
    }

    // phase 2: ex, denom, weighted sum of z_src rows
    float acc = 0.f, dsum = 0.f;
    for (int base = 0; base < deg; base += 64) {
        int n = min(64, deg - base);
        int i = base + lane;
        int s = 0;
        float ex = 0.f;
        if (i < deg) {
            s = csr_src[s0 + i];
            s = ((unsigned)s < (unsigned)NSRC) ? s : 0;
            float e = el[s] + er_d;
            e = (e > 0.f) ? e : SLOPE * e;
            ex = __expf(e - m);
        }
        dsum += ex;
        for (int j = 0; j < n; ++j) {
            int sj = __shfl(s, j);
            float exj = __shfl(ex, j);
            acc = fmaf(exj, z_src[sj * OUTD + lane], acc);
        }
    }
#pragma unroll
    for (int off = 32; off; off >>= 1) dsum += __shfl_xor(dsum, off);

    out[d * OUTD + lane] = (deg > 0 && dsum > 0.f) ? acc / dsum : 0.f;
}

// ---------------------------------------------------------------------------
extern "C" void kernel_launch(void* const* d_in, const int* in_sizes, int n_in,
                              void* d_out, int out_size, void* d_ws, size_t ws_size,
                              hipStream_t stream) {
    const float* h_src   = (const float*)d_in[0];
    const float* h_dst   = (const float*)d_in[1];
    const int*   src_idx = (const int*)d_in[2];
    const int*   dst_idx = (const int*)d_in[3];
    const float* W_src   = (const float*)d_in[4];
    const float* W_dst   = (const float*)d_in[5];
    const float* attn_w  = (const float*)d_in[6];
    const int*   item_u  = (const int*)d_in[7];
    float* out = (float*)d_out;

    // workspace layout (bytes), NO aliasing:
    char* ws = (char*)d_ws;
    float* z_src   = (float*)(ws);                 // 25,600,000
    float* el      = (float*)(ws + 25600000);      //    400,000
    float* er      = (float*)(ws + 26000000);      //    400,000
    int*   cnt     = (int*)  (ws + 26400000);      //    400,000
    int*   starts  = (int*)  (ws + 26800000);      //    400,016 (NDST+1, pad)
    int*   cursor  = (int*)  (ws + 27200016);      //    400,000
    int*   csr_src = (int*)  (ws + 27600016);      //  6,400,000
    float* v_dst   = (float*)(ws + 34000016);      //        512
    const size_t WS_USED = 34000528;

    // Known-zero state every call (harness poisons ws/out with 0xAA).
    hipMemsetAsync(ws, 0, WS_USED, stream);
    hipMemsetAsync(out, 0, (size_t)out_size * sizeof(float), stream);

    k_vdst     <<<1,     128, 0, stream>>>(W_dst, attn_w, v_dst);
    k_zsrc     <<<ZGRID, 256, 0, stream>>>(h_src, W_src, attn_w, item_u, z_src, el);
    k_er       <<<25000, 256, 0, stream>>>(h_dst, v_dst, er);
    k_hist     <<<6250,  256, 0, stream>>>(dst_idx, cnt);
    k_scan     <<<1,     256, 0, stream>>>(cnt, starts, cursor);
    k_fill     <<<6250,  256, 0, stream>>>(src_idx, dst_idx, cursor, csr_src);
    k_aggregate<<<25000, 256, 0, stream>>>(starts, csr_src, el, er, z_src, out);
}

// Round 5
// 510.134 us; speedup vs baseline: 2.1667x; 1.1892x over previous
//
#include <hip/hip_runtime.h>
#include <math.h>

#define NSRC 100000
#define NDST 100000
#define NE   1600000
#define IND  128
#define OUTD 64
#define SLOPE 0.01f
#define NTILE 25     // ceil(NDST / 4096) for the 1024-thread scan
#define ZGRID 1563   // ceil(NSRC / 64)
#define NRANGE 8
#define RSIZE 12500  // NDST / NRANGE
#define NCHUNK 800   // NE / 2000 edges per chunk
#define CHUNK 2000

__device__ __forceinline__ float softplus_f(float x) {
    return (x > 20.f) ? x : log1pf(__expf(x));
}

// ---------------------------------------------------------------------------
// v_dst[k] = sum_o W_dst[o][k] * a_r[o]
__global__ void k_vdst(const float* __restrict__ W_dst,
                       const float* __restrict__ attn_w,
                       float* __restrict__ v_dst) {
    int k = threadIdx.x;  // 128 threads
    float acc = 0.f;
#pragma unroll 8
    for (int o = 0; o < OUTD; ++o)
        acc = fmaf(W_dst[o * IND + k], attn_w[OUTD + o], acc);
    v_dst[k] = acc;
}

// ---------------------------------------------------------------------------
// z_src = h_src @ W_src^T (+softplus), el = z_src @ a_l  (register-tiled, r4)
__global__ __launch_bounds__(256) void k_zsrc(const float* __restrict__ h_src,
                                              const float* __restrict__ W_src,
                                              const float* __restrict__ attn_w,
                                              const int* __restrict__ item_user,
                                              float* __restrict__ z_src,
                                              float* __restrict__ el) {
    __shared__ float4 As4[64 * 17];
    __shared__ float4 Ws4[64 * 17];
    float* Ws = (float*)Ws4;

    const int t   = threadIdx.x;
    const int rg  = t >> 4;
    const int cg  = t & 15;
    const int row0 = blockIdx.x * 64;

    float4 acc[4];
#pragma unroll
    for (int i = 0; i < 4; ++i) acc[i] = float4{0.f, 0.f, 0.f, 0.f};

    for (int p = 0; p < 2; ++p) {
#pragma unroll
        for (int i = 0; i < 4; ++i) {
            int f = i * 256 + t;
            int r = f >> 4, kq = f & 15;
            int row = row0 + r;
            int rowc = (row < NSRC) ? row : (NSRC - 1);
            As4[r * 17 + kq] = *(const float4*)(h_src + rowc * IND + p * 64 + kq * 4);
        }
#pragma unroll
        for (int i = 0; i < 4; ++i) {
            int f = i * 256 + t;
            int o = f >> 4, kq = f & 15;
            float4 w = *(const float4*)(W_src + o * IND + p * 64 + kq * 4);
            Ws[(kq * 4 + 0) * 68 + o] = w.x;
            Ws[(kq * 4 + 1) * 68 + o] = w.y;
            Ws[(kq * 4 + 2) * 68 + o] = w.z;
            Ws[(kq * 4 + 3) * 68 + o] = w.w;
        }
        __syncthreads();

#pragma unroll
        for (int kq = 0; kq < 16; ++kq) {
            float4 w0 = Ws4[(kq * 4 + 0) * 17 + cg];
            float4 w1 = Ws4[(kq * 4 + 1) * 17 + cg];
            float4 w2 = Ws4[(kq * 4 + 2) * 17 + cg];
            float4 w3 = Ws4[(kq * 4 + 3) * 17 + cg];
#pragma unroll
            for (int ri = 0; ri < 4; ++ri) {
                float4 a = As4[(rg * 4 + ri) * 17 + kq];
                acc[ri].x = fmaf(a.x, w0.x, fmaf(a.y, w1.x, fmaf(a.z, w2.x, fmaf(a.w, w3.x, acc[ri].x))));
                acc[ri].y = fmaf(a.x, w0.y, fmaf(a.y, w1.y, fmaf(a.z, w2.y, fmaf(a.w, w3.y, acc[ri].y))));
                acc[ri].z = fmaf(a.x, w0.z, fmaf(a.y, w1.z, fmaf(a.z, w2.z, fmaf(a.w, w3.z, acc[ri].z))));
                acc[ri].w = fmaf(a.x, w0.w, fmaf(a.y, w1.w, fmaf(a.z, w2.w, fmaf(a.w, w3.w, acc[ri].w))));
            }
        }
        __syncthreads();
    }

    const int iu = *item_user;
    const float4 al = *(const float4*)(attn_w + cg * 4);
#pragma unroll
    for (int ri = 0; ri < 4; ++ri) {
        float4 z = acc[ri];
        if (iu) { z.x = softplus_f(z.x); z.y = softplus_f(z.y);
                  z.z = softplus_f(z.z); z.w = softplus_f(z.w); }
        const int row = row0 + rg * 4 + ri;
        float pl = fmaf(z.x, al.x, fmaf(z.y, al.y, fmaf(z.z, al.z, z.w * al.w)));
        pl += __shfl_xor(pl, 1);
        pl += __shfl_xor(pl, 2);
        pl += __shfl_xor(pl, 4);
        pl += __shfl_xor(pl, 8);
        if (row < NSRC) {
            *(float4*)(z_src + row * OUTD + cg * 4) = z;
            if (cg == 0) el[row] = pl;
        }
    }
}

// ---------------------------------------------------------------------------
// er[row] = h_dst[row] . v_dst
__global__ __launch_bounds__(256) void k_er(const float* __restrict__ h_dst,
                                            const float* __restrict__ v_dst,
                                            float* __restrict__ er) {
    __shared__ float v[IND];
    const int tid = threadIdx.x;
    if (tid < IND) v[tid] = v_dst[tid];
    __syncthreads();
    const int wave = tid >> 6, lane = tid & 63;
    const int row = blockIdx.x * 4 + wave;
    const float2 h2 = *(const float2*)(h_dst + row * IND + lane * 2);
    float t = fmaf(h2.x, v[lane * 2], h2.y * v[lane * 2 + 1]);
#pragma unroll
    for (int off = 32; off; off >>= 1) t += __shfl_down(t, off);
    if (lane == 0) er[row] = t;
}

// ---------------------------------------------------------------------------
__global__ void k_hist(const int* __restrict__ dst, int* __restrict__ cnt) {
    int j = blockIdx.x * 256 + threadIdx.x;
    if (j < NE) atomicAdd(&cnt[dst[j]], 1);
}

__device__ __forceinline__ int wave_incl_scan(int v, int lane) {
#pragma unroll
    for (int off = 1; off < 64; off <<= 1) {
        int u = __shfl_up(v, off);
        if (lane >= off) v += u;
    }
    return v;
}

// Single-block exclusive scan (1024 threads, 25 tiles of 4096).
__global__ __launch_bounds__(1024) void k_scan(const int* __restrict__ cnt,
                                               int* __restrict__ starts,
                                               int* __restrict__ cursor) {
    __shared__ int wsum[16];
    __shared__ int carry_s;
    const int t = threadIdx.x, wave = t >> 6, lane = t & 63;
    if (t == 0) carry_s = 0;
    __syncthreads();
    for (int tile = 0; tile < NTILE; ++tile) {
        const int base = tile * 4096 + t * 4;
        int v[4];
#pragma unroll
        for (int q = 0; q < 4; ++q) v[q] = (base + q < NDST) ? cnt[base + q] : 0;
        int tsum = v[0] + v[1] + v[2] + v[3];
        int incl = wave_incl_scan(tsum, lane);
        if (lane == 63) wsum[wave] = incl;
        __syncthreads();
        const int carry = carry_s;
        int wbase = 0;
        for (int w = 0; w < wave; ++w) wbase += wsum[w];
        int run = carry + wbase + incl - tsum;
#pragma unroll
        for (int q = 0; q < 4; ++q) {
            if (base + q < NDST) { starts[base + q] = run; cursor[base + q] = run; }
            run += v[q];
        }
        __syncthreads();
        if (t == 1023) carry_s = carry + wbase + incl;
        __syncthreads();
    }
    if (t == 0) starts[NDST] = carry_s;
}

// ---------------------------------------------------------------------------
// Bucketed fill: block b -> dst range (b&7), edge chunk (b>>3).
// Consecutive blocks round-robin XCDs, so each XCD's csr stores stay in a
// ~1.6 MB window resident in its L2 -> write-combined. Also precomputes
// csr_e = leaky_relu(el[s] + er[d]) so aggregate has no gather chain.
__global__ __launch_bounds__(256) void k_fill(const int* __restrict__ src,
                                              const int* __restrict__ dst,
                                              const float* __restrict__ el,
                                              const float* __restrict__ er,
                                              int* __restrict__ cursor,
                                              int* __restrict__ csr_src,
                                              float* __restrict__ csr_e) {
    const int r  = blockIdx.x & (NRANGE - 1);
    const int c  = blockIdx.x >> 3;
    const int lo = r * RSIZE, hi = lo + RSIZE;
    const int jend = (c + 1) * CHUNK;
    for (int j = c * CHUNK + threadIdx.x; j < jend; j += 256) {
        int d = dst[j];
        if (d >= lo && d < hi) {
            int s = src[j];
            float e = el[s] + er[d];
            e = (e > 0.f) ? e : SLOPE * e;
            int p = atomicAdd(&cursor[d], 1);
            if ((unsigned)p < (unsigned)NE) {
                csr_src[p] = s;
                csr_e[p] = e;
            }
        }
    }
}

// ---------------------------------------------------------------------------
// One wave per dst. Phase 1: coalesced max over csr_e. Phase 2: 4 edges per
// iteration; 16-lane group g handles edge base+g, loads a full z row as
// float4 per lane (256B coalesced). No shuffles in the inner loop.
__global__ __launch_bounds__(256) void k_aggregate(const int* __restrict__ starts,
                                                   const int* __restrict__ csr_src,
                                                   const float* __restrict__ csr_e,
                                                   const float* __restrict__ z_src,
                                                   float* __restrict__ out) {
    const int wave = threadIdx.x >> 6, lane = threadIdx.x & 63;
    const int g = lane >> 4, gl = lane & 15;
    const int d = blockIdx.x * 4 + wave;   // grid 25000 -> exactly NDST
    int s0 = starts[d], s1 = starts[d + 1];
    s0 = max(0, min(s0, NE));
    s1 = max(s0, min(s1, NE));
    const int deg = s1 - s0;

    // phase 1: segment max (coalesced reads of precomputed e)
    float m = -INFINITY;
    for (int base = 0; base < deg; base += 64) {
        int i = base + lane;
        float e = (i < deg) ? csr_e[s0 + i] : -INFINITY;
#pragma unroll
        for (int off = 32; off; off >>= 1) e = fmaxf(e, __shfl_xor(e, off));
        m = fmaxf(m, e);
    }

    // phase 2: weighted sum, 4 edges / iteration
    float4 acc = float4{0.f, 0.f, 0.f, 0.f};
    float dsum = 0.f;
    for (int base = 0; base < deg; base += 4) {
        int i = base + g;
        if (i < deg) {
            float ex = __expf(csr_e[s0 + i] - m);   // same addr across group: broadcast
            int s = csr_src[s0 + i];
            s = ((unsigned)s < (unsigned)NSRC) ? s : 0;
            const float4 z = *(const float4*)(z_src + s * OUTD + gl * 4);
            acc.x = fmaf(ex, z.x, acc.x);
            acc.y = fmaf(ex, z.y, acc.y);
            acc.z = fmaf(ex, z.z, acc.z);
            acc.w = fmaf(ex, z.w, acc.w);
            if (gl == 0) dsum += ex;
        }
    }
    // combine the 4 groups (xor 16, 32)
#pragma unroll
    for (int off = 16; off <= 32; off <<= 1) {
        acc.x += __shfl_xor(acc.x, off);
        acc.y += __shfl_xor(acc.y, off);
        acc.z += __shfl_xor(acc.z, off);
        acc.w += __shfl_xor(acc.w, off);
    }
#pragma unroll
    for (int off = 32; off; off >>= 1) dsum += __shfl_xor(dsum, off);

    if (g == 0) {
        float inv = (deg > 0 && dsum > 0.f) ? 1.f / dsum : 0.f;
        float4 o = float4{acc.x * inv, acc.y * inv, acc.z * inv, acc.w * inv};
        *(float4*)(out + d * OUTD + gl * 4) = o;
    }
}

// ---------------------------------------------------------------------------
extern "C" void kernel_launch(void* const* d_in, const int* in_sizes, int n_in,
                              void* d_out, int out_size, void* d_ws, size_t ws_size,
                              hipStream_t stream) {
    const float* h_src   = (const float*)d_in[0];
    const float* h_dst   = (const float*)d_in[1];
    const int*   src_idx = (const int*)d_in[2];
    const int*   dst_idx = (const int*)d_in[3];
    const float* W_src   = (const float*)d_in[4];
    const float* W_dst   = (const float*)d_in[5];
    const float* attn_w  = (const float*)d_in[6];
    const int*   item_u  = (const int*)d_in[7];
    float* out = (float*)d_out;

    // workspace layout (bytes), NO aliasing:
    char* ws = (char*)d_ws;
    float* z_src   = (float*)(ws);                 // 25,600,000
    float* el      = (float*)(ws + 25600000);      //    400,000
    float* er      = (float*)(ws + 26000000);      //    400,000
    int*   cnt     = (int*)  (ws + 26400000);      //    400,000
    int*   starts  = (int*)  (ws + 26800000);      //    400,016 (NDST+1, pad)
    int*   cursor  = (int*)  (ws + 27200016);      //    400,000
    int*   csr_src = (int*)  (ws + 27600016);      //  6,400,000
    float* csr_e   = (float*)(ws + 34000016);      //  6,400,000
    float* v_dst   = (float*)(ws + 40400016);      //        512
    // total ~40.4 MB

    // cnt is accumulate-into (must be 0); csr_* memset is cheap insurance.
    hipMemsetAsync(cnt, 0, 400000, stream);
    hipMemsetAsync(csr_src, 0, 12800000, stream);   // csr_src + csr_e contiguous

    k_vdst     <<<1,      128,  0, stream>>>(W_dst, attn_w, v_dst);
    k_zsrc     <<<ZGRID,  256,  0, stream>>>(h_src, W_src, attn_w, item_u, z_src, el);
    k_er       <<<25000,  256,  0, stream>>>(h_dst, v_dst, er);
    k_hist     <<<6250,   256,  0, stream>>>(dst_idx, cnt);
    k_scan     <<<1,      1024, 0, stream>>>(cnt, starts, cursor);
    k_fill     <<<NCHUNK * NRANGE, 256, 0, stream>>>(src_idx, dst_idx, el, er,
                                                     cursor, csr_src, csr_e);
    k_aggregate<<<25000,  256,  0, stream>>>(starts, csr_src, csr_e, z_src, out);
}

// Round 6
// 499.717 us; speedup vs baseline: 2.2118x; 1.0208x over previous
//
#include <hip/hip_runtime.h>
#include <math.h>

#define NSRC 100000
#define NDST 100000
#define NE   1600000
#define IND  128
#define OUTD 64
#define SLOPE 0.01f
#define NTILE 25          // scan: ceil(NDST/4096)

#define ZTILES 1563       // ceil(NSRC/64)
#define ZHALF0 782        // zsrc tiles in launch 1
#define ZHALF1 (ZTILES - ZHALF0)
#define ER_BLOCKS 782     // 128 rows each
#define HIST_BLOCKS 1563
#define NRANGE 8
#define RSIZE (NDST / NRANGE)
#define FCHUNK 4096
#define FILL_BLOCKS 3128  // NRANGE * ceil(NE/FCHUNK) = 8 * 391

typedef float f4_t __attribute__((ext_vector_type(4)));
typedef float f2_t __attribute__((ext_vector_type(2)));

__device__ __forceinline__ float4 ntload4(const float* p) {
    f4_t v = __builtin_nontemporal_load((const f4_t*)p);
    return float4{v.x, v.y, v.z, v.w};
}
__device__ __forceinline__ float2 ntload2(const float* p) {
    f2_t v = __builtin_nontemporal_load((const f2_t*)p);
    return float2{v.x, v.y};
}
__device__ __forceinline__ float softplus_f(float x) {
    return (x > 20.f) ? x : log1pf(__expf(x));
}

// ---------------------------------------------------------------------------
// zsrc tile body: 64 rows x 64 cols register-tiled GEMM (+softplus, +el).
// LDS stride 68 floats (16B aligned, ==4 mod 32: conflict-free tiled reads).
__device__ __forceinline__ void zsrc_body(float4* As4, float4* Ws4, int tile,
                                          const float* __restrict__ h_src,
                                          const float* __restrict__ W_src,
                                          const float* __restrict__ attn_w,
                                          int iu,
                                          float* __restrict__ z_src,
                                          float* __restrict__ el) {
    float* Ws = (float*)Ws4;
    const int t  = threadIdx.x;
    const int rg = t >> 4, cg = t & 15;
    const int row0 = tile * 64;

    float4 acc[4];
#pragma unroll
    for (int i = 0; i < 4; ++i) acc[i] = float4{0.f, 0.f, 0.f, 0.f};

    for (int p = 0; p < 2; ++p) {
#pragma unroll
        for (int i = 0; i < 4; ++i) {
            int f = i * 256 + t;
            int r = f >> 4, kq = f & 15;
            int row = row0 + r;
            int rowc = (row < NSRC) ? row : (NSRC - 1);
            As4[r * 17 + kq] = ntload4(h_src + rowc * IND + p * 64 + kq * 4);
        }
#pragma unroll
        for (int i = 0; i < 4; ++i) {
            int f = i * 256 + t;
            int o = f >> 4, kq = f & 15;
            float4 w = *(const float4*)(W_src + o * IND + p * 64 + kq * 4);
            Ws[(kq * 4 + 0) * 68 + o] = w.x;
            Ws[(kq * 4 + 1) * 68 + o] = w.y;
            Ws[(kq * 4 + 2) * 68 + o] = w.z;
            Ws[(kq * 4 + 3) * 68 + o] = w.w;
        }
        __syncthreads();

#pragma unroll
        for (int kq = 0; kq < 16; ++kq) {
            float4 w0 = Ws4[(kq * 4 + 0) * 17 + cg];
            float4 w1 = Ws4[(kq * 4 + 1) * 17 + cg];
            float4 w2 = Ws4[(kq * 4 + 2) * 17 + cg];
            float4 w3 = Ws4[(kq * 4 + 3) * 17 + cg];
#pragma unroll
            for (int ri = 0; ri < 4; ++ri) {
                float4 a = As4[(rg * 4 + ri) * 17 + kq];
                acc[ri].x = fmaf(a.x, w0.x, fmaf(a.y, w1.x, fmaf(a.z, w2.x, fmaf(a.w, w3.x, acc[ri].x))));
                acc[ri].y = fmaf(a.x, w0.y, fmaf(a.y, w1.y, fmaf(a.z, w2.y, fmaf(a.w, w3.y, acc[ri].y))));
                acc[ri].z = fmaf(a.x, w0.z, fmaf(a.y, w1.z, fmaf(a.z, w2.z, fmaf(a.w, w3.z, acc[ri].z))));
                acc[ri].w = fmaf(a.x, w0.w, fmaf(a.y, w1.w, fmaf(a.z, w2.w, fmaf(a.w, w3.w, acc[ri].w))));
            }
        }
        __syncthreads();
    }

    const float4 al = *(const float4*)(attn_w + cg * 4);
#pragma unroll
    for (int ri = 0; ri < 4; ++ri) {
        float4 z = acc[ri];
        if (iu) { z.x = softplus_f(z.x); z.y = softplus_f(z.y);
                  z.z = softplus_f(z.z); z.w = softplus_f(z.w); }
        const int row = row0 + rg * 4 + ri;
        float pl = fmaf(z.x, al.x, fmaf(z.y, al.y, fmaf(z.z, al.z, z.w * al.w)));
        pl += __shfl_xor(pl, 1);
        pl += __shfl_xor(pl, 2);
        pl += __shfl_xor(pl, 4);
        pl += __shfl_xor(pl, 8);
        if (row < NSRC) {
            *(float4*)(z_src + row * OUTD + cg * 4) = z;
            if (cg == 0) el[row] = pl;
        }
    }
}

// ---------------------------------------------------------------------------
// er body: per-block v_dst = W_dst^T a_r (in LDS), then 128 rows of
// er[row] = h_dst[row] . v_dst  (nt float2 loads, wave per row).
__device__ __forceinline__ void er_body(float* smem, int eb,
                                        const float* __restrict__ h_dst,
                                        const float* __restrict__ W_dst,
                                        const float* __restrict__ attn_w,
                                        float* __restrict__ er) {
    float* v = smem;   // 128 floats
    const int t = threadIdx.x;
    if (t < IND) {
        float a = 0.f;
#pragma unroll 8
        for (int o = 0; o < OUTD; ++o)
            a = fmaf(W_dst[o * IND + t], attn_w[OUTD + o], a);
        v[t] = a;
    }
    __syncthreads();
    const int wave = t >> 6, lane = t & 63;
    const int row0 = eb * 128;
#pragma unroll 4
    for (int p = 0; p < 32; ++p) {
        int row = row0 + p * 4 + wave;
        if (row < NDST) {
            float2 h2 = ntload2(h_dst + row * IND + lane * 2);
            float s = fmaf(h2.x, v[lane * 2], h2.y * v[lane * 2 + 1]);
#pragma unroll
            for (int off = 32; off; off >>= 1) s += __shfl_down(s, off);
            if (lane == 0) er[row] = s;
        }
    }
}

// ---------------------------------------------------------------------------
__device__ __forceinline__ void hist_body(int hb, const int* __restrict__ dst,
                                          int* __restrict__ cnt) {
    for (int j = hb * 256 + threadIdx.x; j < NE; j += HIST_BLOCKS * 256) {
        int d = __builtin_nontemporal_load(dst + j);
        atomicAdd(&cnt[d], 1);
    }
}

// ---------------------------------------------------------------------------
// Bucketed fill (csr_src only). nt reads keep the L2 write window resident.
__device__ __forceinline__ void fill_body(int fb, const int* __restrict__ src,
                                          const int* __restrict__ dst,
                                          int* __restrict__ cursor,
                                          int* __restrict__ csr_src) {
    const int r  = fb & (NRANGE - 1);
    const int c  = fb >> 3;
    const int lo = r * RSIZE, hi = lo + RSIZE;
    const int jbeg = c * FCHUNK;
    const int jend = min(NE, jbeg + FCHUNK);
    for (int j = jbeg + threadIdx.x; j < jend; j += 256) {
        int d = __builtin_nontemporal_load(dst + j);
        if (d >= lo && d < hi) {
            int s = __builtin_nontemporal_load(src + j);
            int p = atomicAdd(&cursor[d], 1);
            if ((unsigned)p < (unsigned)NE) csr_src[p] = s;
        }
    }
}

// ---------------------------------------------------------------------------
// Launch 1: [zsrc half0 | er | hist]   (all mutually independent)
__global__ __launch_bounds__(256) void k_p1(const float* __restrict__ h_src,
                                            const float* __restrict__ W_src,
                                            const float* __restrict__ attn_w,
                                            const int* __restrict__ item_user,
                                            const float* __restrict__ h_dst,
                                            const float* __restrict__ W_dst,
                                            const int* __restrict__ dst_idx,
                                            float* __restrict__ z_src,
                                            float* __restrict__ el,
                                            float* __restrict__ er,
                                            int* __restrict__ cnt) {
    __shared__ float4 smem4[64 * 17 * 2];   // 34,816 B
    const int b = blockIdx.x;
    if (b < ZHALF0) {
        zsrc_body(smem4, smem4 + 64 * 17, b, h_src, W_src, attn_w, *item_user, z_src, el);
    } else if (b < ZHALF0 + ER_BLOCKS) {
        er_body((float*)smem4, b - ZHALF0, h_dst, W_dst, attn_w, er);
    } else {
        hist_body(b - ZHALF0 - ER_BLOCKS, dst_idx, cnt);
    }
}

// ---------------------------------------------------------------------------
// Single-block exclusive scan (1024 threads, 25 tiles of 4096).
__device__ __forceinline__ int wave_incl_scan(int v, int lane) {
#pragma unroll
    for (int off = 1; off < 64; off <<= 1) {
        int u = __shfl_up(v, off);
        if (lane >= off) v += u;
    }
    return v;
}

__global__ __launch_bounds__(1024) void k_scan(const int* __restrict__ cnt,
                                               int* __restrict__ starts,
                                               int* __restrict__ cursor) {
    __shared__ int wsum[16];
    __shared__ int carry_s;
    const int t = threadIdx.x, wave = t >> 6, lane = t & 63;
    if (t == 0) carry_s = 0;
    __syncthreads();
    for (int tile = 0; tile < NTILE; ++tile) {
        const int base = tile * 4096 + t * 4;
        int v[4];
#pragma unroll
        for (int q = 0; q < 4; ++q) v[q] = (base + q < NDST) ? cnt[base + q] : 0;
        int tsum = v[0] + v[1] + v[2] + v[3];
        int incl = wave_incl_scan(tsum, lane);
        if (lane == 63) wsum[wave] = incl;
        __syncthreads();
        const int carry = carry_s;
        int wbase = 0;
        for (int w = 0; w < wave; ++w) wbase += wsum[w];
        int run = carry + wbase + incl - tsum;
#pragma unroll
        for (int q = 0; q < 4; ++q) {
            if (base + q < NDST) { starts[base + q] = run; cursor[base + q] = run; }
            run += v[q];
        }
        __syncthreads();
        if (t == 1023) carry_s = carry + wbase + incl;
        __syncthreads();
    }
    if (t == 0) starts[NDST] = carry_s;
}

// ---------------------------------------------------------------------------
// Launch 3: [fill | zsrc half1]
__global__ __launch_bounds__(256) void k_p2(const float* __restrict__ h_src,
                                            const float* __restrict__ W_src,
                                            const float* __restrict__ attn_w,
                                            const int* __restrict__ item_user,
                                            const int* __restrict__ src_idx,
                                            const int* __restrict__ dst_idx,
                                            int* __restrict__ cursor,
                                            int* __restrict__ csr_src,
                                            float* __restrict__ z_src,
                                            float* __restrict__ el) {
    __shared__ float4 smem4[64 * 17 * 2];
    const int b = blockIdx.x;
    if (b < FILL_BLOCKS) {
        fill_body(b, src_idx, dst_idx, cursor, csr_src);
    } else {
        zsrc_body(smem4, smem4 + 64 * 17, ZHALF0 + (b - FILL_BLOCKS),
                  h_src, W_src, attn_w, *item_user, z_src, el);
    }
}

// ---------------------------------------------------------------------------
// One wave per dst. Phase 1: max via el-gather (L2-resident 400 KB table).
// Phase 2: 4 edges/iter, 16-lane groups each load one full z row (float4/lane).
__global__ __launch_bounds__(256) void k_aggregate(const int* __restrict__ starts,
                                                   const int* __restrict__ csr_src,
                                                   const float* __restrict__ el,
                                                   const float* __restrict__ er,
                                                   const float* __restrict__ z_src,
                                                   float* __restrict__ out) {
    const int wave = threadIdx.x >> 6, lane = threadIdx.x & 63;
    const int g = lane >> 4, gl = lane & 15;
    const int d = blockIdx.x * 4 + wave;   // grid 25000 -> exactly NDST
    int s0 = starts[d], s1 = starts[d + 1];
    s0 = max(0, min(s0, NE));
    s1 = max(s0, min(s1, NE));
    const int deg = s1 - s0;
    const float er_d = er[d];

    float m = -INFINITY;
    for (int base = 0; base < deg; base += 64) {
        int i = base + lane;
        float e = -INFINITY;
        if (i < deg) {
            int s = csr_src[s0 + i];
            s = ((unsigned)s < (unsigned)NSRC) ? s : 0;
            e = el[s] + er_d;
            e = (e > 0.f) ? e : SLOPE * e;
        }
#pragma unroll
        for (int off = 32; off; off >>= 1) e = fmaxf(e, __shfl_xor(e, off));
        m = fmaxf(m, e);
    }

    float4 acc = float4{0.f, 0.f, 0.f, 0.f};
    float dsum = 0.f;
    for (int base = 0; base < deg; base += 4) {
        int i = base + g;
        if (i < deg) {
            int s = csr_src[s0 + i];            // same addr across group: broadcast
            s = ((unsigned)s < (unsigned)NSRC) ? s : 0;
            float e = el[s] + er_d;
            e = (e > 0.f) ? e : SLOPE * e;
            float ex = __expf(e - m);
            const float4 z = *(const float4*)(z_src + s * OUTD + gl * 4);
            acc.x = fmaf(ex, z.x, acc.x);
            acc.y = fmaf(ex, z.y, acc.y);
            acc.z = fmaf(ex, z.z, acc.z);
            acc.w = fmaf(ex, z.w, acc.w);
            if (gl == 0) dsum += ex;
        }
    }
#pragma unroll
    for (int off = 16; off <= 32; off <<= 1) {
        acc.x += __shfl_xor(acc.x, off);
        acc.y += __shfl_xor(acc.y, off);
        acc.z += __shfl_xor(acc.z, off);
        acc.w += __shfl_xor(acc.w, off);
    }
#pragma unroll
    for (int off = 32; off; off >>= 1) dsum += __shfl_xor(dsum, off);

    if (g == 0) {
        float inv = (deg > 0 && dsum > 0.f) ? 1.f / dsum : 0.f;
        float4 o = float4{acc.x * inv, acc.y * inv, acc.z * inv, acc.w * inv};
        *(float4*)(out + d * OUTD + gl * 4) = o;
    }
}

// ---------------------------------------------------------------------------
extern "C" void kernel_launch(void* const* d_in, const int* in_sizes, int n_in,
                              void* d_out, int out_size, void* d_ws, size_t ws_size,
                              hipStream_t stream) {
    const float* h_src   = (const float*)d_in[0];
    const float* h_dst   = (const float*)d_in[1];
    const int*   src_idx = (const int*)d_in[2];
    const int*   dst_idx = (const int*)d_in[3];
    const float* W_src   = (const float*)d_in[4];
    const float* W_dst   = (const float*)d_in[5];
    const float* attn_w  = (const float*)d_in[6];
    const int*   item_u  = (const int*)d_in[7];
    float* out = (float*)d_out;

    // workspace layout (bytes), NO aliasing:
    char* ws = (char*)d_ws;
    float* z_src   = (float*)(ws);                 // 25,600,000
    float* el      = (float*)(ws + 25600000);      //    400,000
    float* er      = (float*)(ws + 26000000);      //    400,000
    int*   cnt     = (int*)  (ws + 26400000);      //    400,000
    int*   starts  = (int*)  (ws + 26800000);      //    400,016 (NDST+1, pad)
    int*   cursor  = (int*)  (ws + 27200016);      //    400,000
    int*   csr_src = (int*)  (ws + 27600016);      //  6,400,000
    // total ~34.0 MB

    // cnt must be zero (hist accumulates); csr memset is poison insurance.
    hipMemsetAsync(cnt, 0, 400000, stream);
    hipMemsetAsync(csr_src, 0, 6400000, stream);

    k_p1       <<<ZHALF0 + ER_BLOCKS + HIST_BLOCKS, 256, 0, stream>>>(
                    h_src, W_src, attn_w, item_u, h_dst, W_dst, dst_idx,
                    z_src, el, er, cnt);
    k_scan     <<<1, 1024, 0, stream>>>(cnt, starts, cursor);
    k_p2       <<<FILL_BLOCKS + ZHALF1, 256, 0, stream>>>(
                    h_src, W_src, attn_w, item_u, src_idx, dst_idx,
                    cursor, csr_src, z_src, el);
    k_aggregate<<<25000, 256, 0, stream>>>(starts, csr_src, el, er, z_src, out);
}

// Round 7
// 369.294 us; speedup vs baseline: 2.9930x; 1.3532x over previous
//
#include <hip/hip_runtime.h>
#include <math.h>

#define NSRC 100000
#define NDST 100000
#define NE   1600000
#define IND  128
#define OUTD 64
#define SLOPE 0.01f

#define ZTILES 1563       // ceil(NSRC/64)
#define ER_BLOCKS 782     // 128 rows each
#define HIST_BLOCKS 1563
#define P1_BLOCKS (ZTILES + ER_BLOCKS + HIST_BLOCKS)
#define NRANGE 8
#define RSIZE (NDST / NRANGE)
#define FCHUNK 4096
#define NFCH 391          // ceil(NE/FCHUNK)
#define FILL_BLOCKS (NRANGE * NFCH)
#define SCAN_BLOCKS 25    // 25 * 4096 >= NDST

typedef float f4_t __attribute__((ext_vector_type(4)));
typedef float f2_t __attribute__((ext_vector_type(2)));

__device__ __forceinline__ float4 ntload4(const float* p) {
    f4_t v = __builtin_nontemporal_load((const f4_t*)p);
    return float4{v.x, v.y, v.z, v.w};
}
__device__ __forceinline__ float2 ntload2(const float* p) {
    f2_t v = __builtin_nontemporal_load((const f2_t*)p);
    return float2{v.x, v.y};
}
__device__ __forceinline__ float softplus_f(float x) {
    return (x > 20.f) ? x : log1pf(__expf(x));
}
__device__ __forceinline__ unsigned short f2bf(float f) {
    unsigned u = __float_as_uint(f);
    return (unsigned short)((u + 0x7FFFu + ((u >> 16) & 1u)) >> 16);
}
__device__ __forceinline__ float bf2f(unsigned short h) {
    return __uint_as_float(((unsigned)h) << 16);
}

// ---------------------------------------------------------------------------
// zsrc tile: 64x64 register-tiled GEMM (+softplus). Writes z16 (bf16) + el.
__device__ __forceinline__ void zsrc_body(float4* As4, float4* Ws4, int tile,
                                          const float* __restrict__ h_src,
                                          const float* __restrict__ W_src,
                                          const float* __restrict__ attn_w,
                                          int iu,
                                          unsigned short* __restrict__ z16,
                                          float* __restrict__ el) {
    float* Ws = (float*)Ws4;
    const int t  = threadIdx.x;
    const int rg = t >> 4, cg = t & 15;
    const int row0 = tile * 64;

    float4 acc[4];
#pragma unroll
    for (int i = 0; i < 4; ++i) acc[i] = float4{0.f, 0.f, 0.f, 0.f};

    for (int p = 0; p < 2; ++p) {
#pragma unroll
        for (int i = 0; i < 4; ++i) {
            int f = i * 256 + t;
            int r = f >> 4, kq = f & 15;
            int row = row0 + r;
            int rowc = (row < NSRC) ? row : (NSRC - 1);
            As4[r * 17 + kq] = ntload4(h_src + rowc * IND + p * 64 + kq * 4);
        }
#pragma unroll
        for (int i = 0; i < 4; ++i) {
            int f = i * 256 + t;
            int o = f >> 4, kq = f & 15;
            float4 w = *(const float4*)(W_src + o * IND + p * 64 + kq * 4);
            Ws[(kq * 4 + 0) * 68 + o] = w.x;
            Ws[(kq * 4 + 1) * 68 + o] = w.y;
            Ws[(kq * 4 + 2) * 68 + o] = w.z;
            Ws[(kq * 4 + 3) * 68 + o] = w.w;
        }
        __syncthreads();

#pragma unroll
        for (int kq = 0; kq < 16; ++kq) {
            float4 w0 = Ws4[(kq * 4 + 0) * 17 + cg];
            float4 w1 = Ws4[(kq * 4 + 1) * 17 + cg];
            float4 w2 = Ws4[(kq * 4 + 2) * 17 + cg];
            float4 w3 = Ws4[(kq * 4 + 3) * 17 + cg];
#pragma unroll
            for (int ri = 0; ri < 4; ++ri) {
                float4 a = As4[(rg * 4 + ri) * 17 + kq];
                acc[ri].x = fmaf(a.x, w0.x, fmaf(a.y, w1.x, fmaf(a.z, w2.x, fmaf(a.w, w3.x, acc[ri].x))));
                acc[ri].y = fmaf(a.x, w0.y, fmaf(a.y, w1.y, fmaf(a.z, w2.y, fmaf(a.w, w3.y, acc[ri].y))));
                acc[ri].z = fmaf(a.x, w0.z, fmaf(a.y, w1.z, fmaf(a.z, w2.z, fmaf(a.w, w3.z, acc[ri].z))));
                acc[ri].w = fmaf(a.x, w0.w, fmaf(a.y, w1.w, fmaf(a.z, w2.w, fmaf(a.w, w3.w, acc[ri].w))));
            }
        }
        __syncthreads();
    }

    const float4 al = *(const float4*)(attn_w + cg * 4);
#pragma unroll
    for (int ri = 0; ri < 4; ++ri) {
        float4 z = acc[ri];
        if (iu) { z.x = softplus_f(z.x); z.y = softplus_f(z.y);
                  z.z = softplus_f(z.z); z.w = softplus_f(z.w); }
        const int row = row0 + rg * 4 + ri;
        float pl = fmaf(z.x, al.x, fmaf(z.y, al.y, fmaf(z.z, al.z, z.w * al.w)));
        pl += __shfl_xor(pl, 1);
        pl += __shfl_xor(pl, 2);
        pl += __shfl_xor(pl, 4);
        pl += __shfl_xor(pl, 8);
        if (row < NSRC) {
            ushort4 zz;
            zz.x = f2bf(z.x); zz.y = f2bf(z.y); zz.z = f2bf(z.z); zz.w = f2bf(z.w);
            *(ushort4*)(z16 + row * OUTD + cg * 4) = zz;   // 16 lanes -> 128B line
            if (cg == 0) el[row] = pl;
        }
    }
}

// ---------------------------------------------------------------------------
// er: per-block v_dst = W_dst^T a_r in LDS, then 128 rows of h_dst . v_dst
__device__ __forceinline__ void er_body(float* smem, int eb,
                                        const float* __restrict__ h_dst,
                                        const float* __restrict__ W_dst,
                                        const float* __restrict__ attn_w,
                                        float* __restrict__ er) {
    float* v = smem;
    const int t = threadIdx.x;
    if (t < IND) {
        float a = 0.f;
#pragma unroll 8
        for (int o = 0; o < OUTD; ++o)
            a = fmaf(W_dst[o * IND + t], attn_w[OUTD + o], a);
        v[t] = a;
    }
    __syncthreads();
    const int wave = t >> 6, lane = t & 63;
    const int row0 = eb * 128;
#pragma unroll 4
    for (int p = 0; p < 32; ++p) {
        int row = row0 + p * 4 + wave;
        if (row < NDST) {
            float2 h2 = ntload2(h_dst + row * IND + lane * 2);
            float s = fmaf(h2.x, v[lane * 2], h2.y * v[lane * 2 + 1]);
#pragma unroll
            for (int off = 32; off; off >>= 1) s += __shfl_down(s, off);
            if (lane == 0) er[row] = s;
        }
    }
}

// ---------------------------------------------------------------------------
__device__ __forceinline__ void hist_body(int hb, const int* __restrict__ dst,
                                          int* __restrict__ cnt) {
    // plain loads: prime L3 with dst for the fill re-reads
    for (int j = hb * 256 + threadIdx.x; j < NE; j += HIST_BLOCKS * 256)
        atomicAdd(&cnt[dst[j]], 1);
}

// ---------------------------------------------------------------------------
// Launch 1: [zsrc (all) | er | hist]  (mutually independent)
__global__ __launch_bounds__(256) void k_p1(const float* __restrict__ h_src,
                                            const float* __restrict__ W_src,
                                            const float* __restrict__ attn_w,
                                            const int* __restrict__ item_user,
                                            const float* __restrict__ h_dst,
                                            const float* __restrict__ W_dst,
                                            const int* __restrict__ dst_idx,
                                            unsigned short* __restrict__ z16,
                                            float* __restrict__ el,
                                            float* __restrict__ er,
                                            int* __restrict__ cnt) {
    __shared__ float4 smem4[64 * 17 * 2];   // 34,816 B
    const int b = blockIdx.x;
    if (b < ZTILES) {
        zsrc_body(smem4, smem4 + 64 * 17, b, h_src, W_src, attn_w, *item_user, z16, el);
    } else if (b < ZTILES + ER_BLOCKS) {
        er_body((float*)smem4, b - ZTILES, h_dst, W_dst, attn_w, er);
    } else {
        hist_body(b - ZTILES - ER_BLOCKS, dst_idx, cnt);
    }
}

// ---------------------------------------------------------------------------
// Parallel scan: 25 local blocks -> 1-wave top scan -> addbase
__device__ __forceinline__ int wave_incl_scan(int v, int lane) {
#pragma unroll
    for (int off = 1; off < 64; off <<= 1) {
        int u = __shfl_up(v, off);
        if (lane >= off) v += u;
    }
    return v;
}

__global__ __launch_bounds__(1024) void k_scan_local(const int* __restrict__ cnt,
                                                     int* __restrict__ starts,
                                                     int* __restrict__ blocksum) {
    __shared__ int wsum[16];
    const int t = threadIdx.x, wave = t >> 6, lane = t & 63;
    const int base = blockIdx.x * 4096 + t * 4;
    int v[4];
#pragma unroll
    for (int q = 0; q < 4; ++q) v[q] = (base + q < NDST) ? cnt[base + q] : 0;
    int tsum = v[0] + v[1] + v[2] + v[3];
    int incl = wave_incl_scan(tsum, lane);
    if (lane == 63) wsum[wave] = incl;
    __syncthreads();
    int wbase = 0;
    for (int w = 0; w < wave; ++w) wbase += wsum[w];
    int run = wbase + incl - tsum;
#pragma unroll
    for (int q = 0; q < 4; ++q) {
        if (base + q < NDST) starts[base + q] = run;
        run += v[q];
    }
    if (t == 1023) blocksum[blockIdx.x] = wbase + incl;
}

__global__ void k_scan_top(int* __restrict__ blocksum, int* __restrict__ starts) {
    const int lane = threadIdx.x;   // 64 threads, 1 block
    int v = (lane < SCAN_BLOCKS) ? blocksum[lane] : 0;
    int incl = wave_incl_scan(v, lane);
    if (lane < SCAN_BLOCKS) blocksum[lane] = incl - v;   // exclusive base
    if (lane == SCAN_BLOCKS - 1) starts[NDST] = incl;    // == NE
}

__global__ __launch_bounds__(1024) void k_addbase(int* __restrict__ starts,
                                                  const int* __restrict__ blocksum,
                                                  int* __restrict__ cursor) {
    const int base = blockIdx.x * 4096 + threadIdx.x * 4;
    const int add = blocksum[blockIdx.x];
#pragma unroll
    for (int q = 0; q < 4; ++q) {
        int idx = base + q;
        if (idx < NDST) {
            int s = starts[idx] + add;
            starts[idx] = s;
            cursor[idx] = s;
        }
    }
}

// ---------------------------------------------------------------------------
// Bucketed fill, own kernel: 8 VGPR, no LDS -> max occupancy hides
// scatter/atomic latency. Plain loads (dst/src served from L3 after hist).
__global__ __launch_bounds__(256) void k_fill(const int* __restrict__ src,
                                              const int* __restrict__ dst,
                                              int* __restrict__ cursor,
                                              int* __restrict__ csr_src) {
    const int r  = blockIdx.x & (NRANGE - 1);
    const int c  = blockIdx.x >> 3;
    const int lo = r * RSIZE, hi = lo + RSIZE;
    const int jbeg = c * FCHUNK;
    const int jend = min(NE, jbeg + FCHUNK);
    for (int j = jbeg + threadIdx.x; j < jend; j += 256) {
        int d = dst[j];
        if (d >= lo && d < hi) {
            int s = src[j];
            int p = atomicAdd(&cursor[d], 1);
            if ((unsigned)p < (unsigned)NE) csr_src[p] = s;
        }
    }
}

// ---------------------------------------------------------------------------
// One wave per dst, single pass (no segment-max: leaky outputs are bounded,
// |e| <~ 12, exp(e) in [0.88, 2e5] -> fp32-safe; ratios identical).
// 4 edges/iter; 16-lane group g does edge base+g; lane gl loads 4 bf16 z.
__global__ __launch_bounds__(256) void k_aggregate(const int* __restrict__ starts,
                                                   const int* __restrict__ csr_src,
                                                   const float* __restrict__ el,
                                                   const float* __restrict__ er,
                                                   const unsigned short* __restrict__ z16,
                                                   float* __restrict__ out) {
    const int wave = threadIdx.x >> 6, lane = threadIdx.x & 63;
    const int g = lane >> 4, gl = lane & 15;
    const int d = blockIdx.x * 4 + wave;   // grid 25000 -> exactly NDST
    int s0 = starts[d], s1 = starts[d + 1];
    s0 = max(0, min(s0, NE));
    s1 = max(s0, min(s1, NE));
    const int deg = s1 - s0;
    const float er_d = er[d];

    float4 acc = float4{0.f, 0.f, 0.f, 0.f};
    float dsum = 0.f;
    for (int base = 0; base < deg; base += 4) {
        int i = base + g;
        if (i < deg) {
            int s = csr_src[s0 + i];           // same addr across 16-lane group
            s = ((unsigned)s < (unsigned)NSRC) ? s : 0;
            float e = el[s] + er_d;
            e = (e > 0.f) ? e : SLOPE * e;
            float ex = __expf(e);
            ushort4 zz = *(const ushort4*)(z16 + s * OUTD + gl * 4);
            acc.x = fmaf(ex, bf2f(zz.x), acc.x);
            acc.y = fmaf(ex, bf2f(zz.y), acc.y);
            acc.z = fmaf(ex, bf2f(zz.z), acc.z);
            acc.w = fmaf(ex, bf2f(zz.w), acc.w);
            if (gl == 0) dsum += ex;
        }
    }
#pragma unroll
    for (int off = 16; off <= 32; off <<= 1) {
        acc.x += __shfl_xor(acc.x, off);
        acc.y += __shfl_xor(acc.y, off);
        acc.z += __shfl_xor(acc.z, off);
        acc.w += __shfl_xor(acc.w, off);
    }
#pragma unroll
    for (int off = 32; off; off >>= 1) dsum += __shfl_xor(dsum, off);

    if (g == 0) {
        float inv = (deg > 0 && dsum > 0.f) ? 1.f / dsum : 0.f;
        float4 o = float4{acc.x * inv, acc.y * inv, acc.z * inv, acc.w * inv};
        *(float4*)(out + d * OUTD + gl * 4) = o;
    }
}

// ---------------------------------------------------------------------------
extern "C" void kernel_launch(void* const* d_in, const int* in_sizes, int n_in,
                              void* d_out, int out_size, void* d_ws, size_t ws_size,
                              hipStream_t stream) {
    const float* h_src   = (const float*)d_in[0];
    const float* h_dst   = (const float*)d_in[1];
    const int*   src_idx = (const int*)d_in[2];
    const int*   dst_idx = (const int*)d_in[3];
    const float* W_src   = (const float*)d_in[4];
    const float* W_dst   = (const float*)d_in[5];
    const float* attn_w  = (const float*)d_in[6];
    const int*   item_u  = (const int*)d_in[7];
    float* out = (float*)d_out;

    // workspace layout (bytes), NO aliasing:
    char* ws = (char*)d_ws;
    unsigned short* z16 = (unsigned short*)(ws);   // 12,800,000
    float* el       = (float*)(ws + 12800000);     //    400,000
    float* er       = (float*)(ws + 13200000);     //    400,000
    int*   cnt      = (int*)  (ws + 13600000);     //    400,000
    int*   starts   = (int*)  (ws + 14000000);     //    400,016 (NDST+1, pad)
    int*   cursor   = (int*)  (ws + 14400016);     //    400,000
    int*   csr_src  = (int*)  (ws + 14800016);     //  6,400,000
    int*   blocksum = (int*)  (ws + 21200016);     //        128
    // total ~21.2 MB

    hipMemsetAsync(cnt, 0, 400000, stream);        // hist accumulates
    hipMemsetAsync(csr_src, 0, 6400000, stream);   // poison insurance

    k_p1        <<<P1_BLOCKS,   256,  0, stream>>>(h_src, W_src, attn_w, item_u,
                                                   h_dst, W_dst, dst_idx,
                                                   z16, el, er, cnt);
    k_scan_local<<<SCAN_BLOCKS, 1024, 0, stream>>>(cnt, starts, blocksum);
    k_scan_top  <<<1,           64,   0, stream>>>(blocksum, starts);
    k_addbase   <<<SCAN_BLOCKS, 1024, 0, stream>>>(starts, blocksum, cursor);
    k_fill      <<<FILL_BLOCKS, 256,  0, stream>>>(src_idx, dst_idx, cursor, csr_src);
    k_aggregate <<<25000,       256,  0, stream>>>(starts, csr_src, el, er, z16, out);
}